// Round 1
// baseline (5000.511 us; speedup 1.0000x reference)
//
#include <hip/hip_runtime.h>
#include <math.h>

// Contrastive loss forward, fp32 baseline.
// Pipeline: conv1x1 (xb->tb) ; 16x encoder passes {conv3x3 s2 p1 -> BN(train) ->
// leaky -> GAP -> 2xFC} ; normalize + exp-sim einsums -> (geo_loss, sem_loss).
// ws layout (floats): tb[4] | wt3[2] | wt1[4] | y[16] | mv | fea | enc  (~227 MB)

#define DEV static __device__ __forceinline__

DEV float leaky_f(float x) { return x > 0.f ? x : 0.1f * x; }
DEV float4 ld4(const float* p) { return *(const float4*)p; }

// ---------------- weight transposes (one-time, coalesced-staging layouts) ----
__global__ void tw3_k(const float* __restrict__ loc_cw, const float* __restrict__ sem_cw,
                      float* __restrict__ wt_loc, float* __restrict__ wt_sem) {
  const int N = 256 * 256 * 9;
  for (int idx = blockIdx.x * 256 + threadIdx.x; idx < 2 * N; idx += gridDim.x * 256) {
    int set = idx / N;
    int r = idx - set * N;           // r = (ci*9+k)*256 + co
    int co = r & 255;
    int q = r >> 8;
    int k = q % 9, ci = q / 9;
    const float* src = set ? sem_cw : loc_cw;
    float* dst = set ? wt_sem : wt_loc;
    dst[r] = src[(co * 256 + ci) * 9 + k];
  }
}

struct TW1Args { const float* w[4]; float* wt[4]; int cin[4]; };
__global__ void tw1_k(TW1Args a) {
  int s = blockIdx.y;
  int cin = a.cin[s];
  int N = cin * 256;
  const float* w = a.w[s];
  float* wt = a.wt[s];
  for (int idx = blockIdx.x * 256 + threadIdx.x; idx < N; idx += gridDim.x * 256) {
    int co = idx & 255, ci = idx >> 8;   // wt[ci][co]
    wt[idx] = w[co * cin + ci];
  }
}

// ---------------- conv1x1: out[b,co,p] = bias[co] + sum_ci w[co,ci]*x[b,ci,p] --
struct Conv1Args { const float* x; const float* wt; const float* bias; float* out; int Cin; int HW; };
__global__ __launch_bounds__(256) void conv1x1_k(Conv1Args a) {
  __shared__ float sX[8][128];
  __shared__ float sW[8][64];
  const int tid = threadIdx.x;
  const int p0 = blockIdx.x * 128;
  const int co0 = blockIdx.y * 64;
  const int b = blockIdx.z;
  const float* x = a.x + (size_t)b * a.Cin * a.HW;
  float* out = a.out + (size_t)b * 256 * a.HW;
  const int cog = tid >> 4;        // 16 groups of 4 co
  const int posg = tid & 15;       // 16 groups of 8 positions
  const bool aligned4 = ((a.HW & 3) == 0);

  float acc[4][8];
#pragma unroll
  for (int i = 0; i < 4; i++)
#pragma unroll
    for (int j = 0; j < 8; j++) acc[i][j] = 0.f;

  for (int ci0 = 0; ci0 < a.Cin; ci0 += 8) {
    __syncthreads();
    {  // stage x tile: 8 ci x 128 pos (256 float4)
      int ci = tid >> 5, c4 = tid & 31;
      int p = p0 + c4 * 4;
      const float* src = x + (size_t)(ci0 + ci) * a.HW;
      float4 v = make_float4(0.f, 0.f, 0.f, 0.f);
      if (aligned4 && p + 3 < a.HW) {
        v = ld4(src + p);
      } else {
        float t0 = (p + 0 < a.HW) ? src[p + 0] : 0.f;
        float t1 = (p + 1 < a.HW) ? src[p + 1] : 0.f;
        float t2 = (p + 2 < a.HW) ? src[p + 2] : 0.f;
        float t3 = (p + 3 < a.HW) ? src[p + 3] : 0.f;
        v = make_float4(t0, t1, t2, t3);
      }
      *(float4*)&sX[ci][c4 * 4] = v;
    }
    if (tid < 128) {  // stage w tile: 8 ci x 64 co (transposed layout: contiguous)
      int ci = tid >> 4, c4 = tid & 15;
      *(float4*)&sW[ci][c4 * 4] = ld4(&a.wt[(size_t)(ci0 + ci) * 256 + co0 + c4 * 4]);
    }
    __syncthreads();
#pragma unroll
    for (int ci = 0; ci < 8; ci++) {
      float4 wv = *(float4*)&sW[ci][cog * 4];
      float4 x0 = *(float4*)&sX[ci][posg * 8];
      float4 x1 = *(float4*)&sX[ci][posg * 8 + 4];
      float xr[8] = {x0.x, x0.y, x0.z, x0.w, x1.x, x1.y, x1.z, x1.w};
#pragma unroll
      for (int j = 0; j < 8; j++) {
        acc[0][j] += wv.x * xr[j];
        acc[1][j] += wv.y * xr[j];
        acc[2][j] += wv.z * xr[j];
        acc[3][j] += wv.w * xr[j];
      }
    }
  }
#pragma unroll
  for (int i = 0; i < 4; i++) {
    int co = co0 + cog * 4 + i;
    float bias = a.bias[co];
    size_t base = (size_t)co * a.HW;
#pragma unroll
    for (int j = 0; j < 8; j++) {
      int p = p0 + posg * 8 + j;
      if (p < a.HW) out[base + p] = acc[i][j] + bias;
    }
  }
}

// ---------------- conv3x3 stride2 pad1, 4 passes per launch ------------------
struct Conv3Args {
  const float* in[4];   // per-pass input (B,256,H,W)
  const float* wt[4];   // transposed weights [ci][k][co]
  const float* cb[4];
  float* out[4];        // (B,256,OH,OW)
  int H, W, OH, OW, n_ow_t;
};
#define CI_T 4
__global__ __launch_bounds__(256) void conv3x3_k(Conv3Args a) {
  __shared__ float sIn[CI_T][17][36];  // 17x33 patch, stride 36 for aligned float4
  __shared__ float sW[CI_T][9][64];
  const int tid = threadIdx.x;
  const int t_oh = blockIdx.x / a.n_ow_t;
  const int t_ow = blockIdx.x % a.n_ow_t;
  const int co0 = blockIdx.y * 64;
  const int pass = blockIdx.z >> 1, b = blockIdx.z & 1;
  const float* in = a.in[pass] + (size_t)b * 256 * a.H * a.W;
  const float* wt = a.wt[pass];
  float* out = a.out[pass] + (size_t)b * 256 * a.OH * a.OW;
  const int oh0 = t_oh * 8, ow0 = t_ow * 16;
  const int ihp = 2 * oh0 - 1, iwp = 2 * ow0 - 1;

  const int cog = tid >> 4;        // 16 groups of 4 co
  const int posg = tid & 15;       // 8 oh x 2 half-rows
  const int toh = posg >> 1, tow = posg & 1;

  float acc[4][8];
#pragma unroll
  for (int i = 0; i < 4; i++)
#pragma unroll
    for (int j = 0; j < 8; j++) acc[i][j] = 0.f;

  for (int ci0 = 0; ci0 < 256; ci0 += CI_T) {
    __syncthreads();
    // stage input patch: CI_T x 17 x 33 valid elements
    for (int idx = tid; idx < CI_T * 17 * 33; idx += 256) {
      int cip = idx / (17 * 33);
      int rem = idx - cip * (17 * 33);
      int r = rem / 33, c = rem - r * 33;
      int ih = ihp + r, iw = iwp + c;
      float v = 0.f;
      if (ih >= 0 && ih < a.H && iw >= 0 && iw < a.W)
        v = in[(size_t)(ci0 + cip) * a.H * a.W + (size_t)ih * a.W + iw];
      sIn[cip][r][c] = v;
    }
    // stage weights: CI_T*9 rows x 64 co (contiguous in transposed layout)
    for (int idx = tid; idx < CI_T * 9 * 16; idx += 256) {
      int row = idx >> 4, c4 = idx & 15;
      int cip = row / 9, k = row - cip * 9;
      *(float4*)&sW[cip][k][c4 * 4] =
          ld4(&wt[((size_t)(ci0 + cip) * 9 + k) * 256 + co0 + c4 * 4]);
    }
    __syncthreads();
#pragma unroll
    for (int cip = 0; cip < CI_T; cip++) {
#pragma unroll
      for (int kh = 0; kh < 3; kh++) {
        const float* rowp = &sIn[cip][2 * toh + kh][tow * 16];
        float rv[17];
        *(float4*)&rv[0]  = ld4(rowp);
        *(float4*)&rv[4]  = ld4(rowp + 4);
        *(float4*)&rv[8]  = ld4(rowp + 8);
        *(float4*)&rv[12] = ld4(rowp + 12);
        rv[16] = rowp[16];
#pragma unroll
        for (int kw = 0; kw < 3; kw++) {
          float4 wv = *(float4*)&sW[cip][kh * 3 + kw][cog * 4];
#pragma unroll
          for (int j = 0; j < 8; j++) {
            float xv = rv[2 * j + kw];
            acc[0][j] += wv.x * xv;
            acc[1][j] += wv.y * xv;
            acc[2][j] += wv.z * xv;
            acc[3][j] += wv.w * xv;
          }
        }
      }
    }
  }
  const int oh = oh0 + toh;
  if (oh < a.OH) {
#pragma unroll
    for (int i = 0; i < 4; i++) {
      int co = co0 + cog * 4 + i;
      float cb = a.cb[pass][co];
      size_t base = (size_t)co * a.OH * a.OW + (size_t)oh * a.OW;
#pragma unroll
      for (int j = 0; j < 8; j++) {
        int ow = ow0 + tow * 8 + j;
        if (ow < a.OW) out[base + ow] = acc[i][j] + cb;
      }
    }
  }
}

// ---------------- BN stats: mean/var per (pass, channel) over (B, OH, OW) ----
struct RedArgs { const float* y[16]; float* mv; int ohw[16]; };
__global__ __launch_bounds__(256) void bn_reduce_k(RedArgs a) {
  const int c = blockIdx.x, p = blockIdx.y;
  const int ohw = a.ohw[p];
  const float* y = a.y[p];
  float s = 0.f, s2 = 0.f;
  for (int b = 0; b < 2; b++) {
    const float* base = y + ((size_t)b * 256 + c) * ohw;
    for (int i = threadIdx.x; i < ohw; i += 256) {
      float v = base[i];
      s += v; s2 += v * v;
    }
  }
  __shared__ float rs[4], rs2[4];
  for (int off = 32; off > 0; off >>= 1) { s += __shfl_down(s, off); s2 += __shfl_down(s2, off); }
  int wid = threadIdx.x >> 6, lane = threadIdx.x & 63;
  if (lane == 0) { rs[wid] = s; rs2[wid] = s2; }
  __syncthreads();
  if (threadIdx.x == 0) {
    float S = 0.f, S2 = 0.f;
    for (int w = 0; w < 4; w++) { S += rs[w]; S2 += rs2[w]; }
    float n = (float)(2 * ohw);
    float m = S / n;
    a.mv[p * 512 + c] = m;
    a.mv[p * 512 + 256 + c] = S2 / n - m * m;
  }
}

// ---------------- fea[p,b,c] = mean_spatial( leaky(BN(y)) ) ------------------
struct FeaArgs { const float* y[16]; const float* g[16]; const float* beta[16];
                 const float* mv; float* fea; int ohw[16]; };
__global__ __launch_bounds__(256) void fea_k(FeaArgs a) {
  const int c = blockIdx.x;
  const int z = blockIdx.y;
  const int p = z >> 1, b = z & 1;
  const int ohw = a.ohw[p];
  float m = a.mv[p * 512 + c], v = a.mv[p * 512 + 256 + c];
  float rs = 1.0f / sqrtf(v + 1e-5f);
  float gg = a.g[p][c] * rs;
  float bb = a.beta[p][c] - m * gg;
  const float* base = a.y[p] + ((size_t)b * 256 + c) * ohw;
  float s = 0.f;
  for (int i = threadIdx.x; i < ohw; i += 256) {
    float t = base[i] * gg + bb;
    s += leaky_f(t);
  }
  __shared__ float rsm[4];
  for (int off = 32; off > 0; off >>= 1) s += __shfl_down(s, off);
  int wid = threadIdx.x >> 6, lane = threadIdx.x & 63;
  if (lane == 0) rsm[wid] = s;
  __syncthreads();
  if (threadIdx.x == 0) {
    float S = rsm[0] + rsm[1] + rsm[2] + rsm[3];
    a.fea[((size_t)p * 2 + b) * 256 + c] = S / (float)ohw;
  }
}

// ---------------- 2-layer MLP per pass ---------------------------------------
struct MlpArgs { const float* fea; const float* w1[16]; const float* b1[16];
                 const float* w2[16]; const float* b2[16]; float* enc; };
__global__ __launch_bounds__(512) void mlp_k(MlpArgs a) {
  const int p = blockIdx.x;
  const int t = threadIdx.x;
  const int b = t >> 8, co = t & 255;
  __shared__ float sfea[2][256];
  __shared__ float sh[2][256];
  sfea[b][co] = a.fea[((size_t)p * 2 + b) * 256 + co];
  __syncthreads();
  {
    const float* w1 = a.w1[p] + (size_t)co * 256;
    float s = a.b1[p][co];
    for (int ci = 0; ci < 256; ci += 4) {
      float4 wv = ld4(&w1[ci]);
      s += wv.x * sfea[b][ci] + wv.y * sfea[b][ci + 1] + wv.z * sfea[b][ci + 2] + wv.w * sfea[b][ci + 3];
    }
    sh[b][co] = leaky_f(s);
  }
  __syncthreads();
  {
    const float* w2 = a.w2[p] + (size_t)co * 256;
    float s = a.b2[p][co];
    for (int ci = 0; ci < 256; ci += 4) {
      float4 wv = ld4(&w2[ci]);
      s += wv.x * sh[b][ci] + wv.y * sh[b][ci + 1] + wv.z * sh[b][ci + 2] + wv.w * sh[b][ci + 3];
    }
    a.enc[((size_t)p * 2 + b) * 256 + co] = s;
  }
}

// ---------------- final loss: normalize + einsums + logs ---------------------
// enc layout: [g][s][b][c]; g: 0=Lb(tb,loc) 1=L(x,loc) 2=Sb(tb,sem) 3=Sm(x,sem)
__global__ __launch_bounds__(256) void loss_k(const float* __restrict__ enc, float* __restrict__ out) {
  __shared__ float nv[32][256];
  __shared__ float norms[32];
  __shared__ float sE[4][64];
  const int tid = threadIdx.x;
  if (tid < 32) {
    const float* v = enc + (size_t)tid * 256;
    float s = 0.f;
    for (int i = 0; i < 256; i++) s += v[i] * v[i];
    norms[tid] = fmaxf(sqrtf(s), 1e-12f);
  }
  __syncthreads();
  for (int idx = tid; idx < 8192; idx += 256) {
    int vi = idx >> 8, c = idx & 255;
    nv[vi][c] = enc[idx] / norms[vi];
  }
  __syncthreads();
  {
    // m0:(L,L) m1:(L,Lb) m2:(Sm,Sm) m3:(Sm,Sb)
    int m = tid >> 6, e = tid & 63;
    int i = e >> 4, b = (e >> 3) & 1, k = (e >> 1) & 3, l = e & 1;
    int ga = (m < 2) ? 1 : 3;
    int gb = (m == 0) ? 1 : (m == 1) ? 0 : (m == 2) ? 3 : 2;
    const float* va = nv[ga * 8 + i * 2 + b];
    const float* vb = nv[gb * 8 + k * 2 + l];
    float d = 0.f;
    for (int c = 0; c < 256; c++) d += va[c] * vb[c];
    sE[m][e] = expf(d * 2.0f);  // TEMP = 0.5
  }
  __syncthreads();
  if (tid == 0) {
    float geo = 0.f;
    for (int i = 0; i < 4; i++)
      for (int b = 0; b < 2; b++) {
        float num = sE[1][i * 16 + b * 8 + i * 2 + b];
        float den = num;
        for (int k = 0; k < 4; k++)
          for (int l = 0; l < 2; l++)
            if (k != i && l != b)
              den += sE[0][i * 16 + b * 8 + k * 2 + l] + sE[1][i * 16 + b * 8 + k * 2 + l];
        geo -= logf(num / den);
      }
    out[0] = geo;
    float sem = 0.f;
    for (int i = 0; i < 3; i++)
      for (int b = 0; b < 2; b++) {
        float num = sE[2][i * 16 + b * 8 + (i + 1) * 2 + b];
        float den = num;
        for (int k = 0; k < 4; k++)
          for (int l = 0; l < 2; l++)
            if (l != b)
              den += sE[2][i * 16 + b * 8 + k * 2 + l] + sE[3][i * 16 + b * 8 + k * 2 + l];
        sem -= logf(num / den);
      }
    out[1] = sem;
  }
}

// ---------------- host launcher ---------------------------------------------
extern "C" void kernel_launch(void* const* d_in, const int* in_sizes, int n_in,
                              void* d_out, int out_size, void* d_ws, size_t ws_size,
                              hipStream_t stream) {
  (void)in_sizes; (void)n_in; (void)out_size; (void)ws_size;
  const float* xb[4] = {(const float*)d_in[0], (const float*)d_in[1],
                        (const float*)d_in[2], (const float*)d_in[3]};
  const float* xs[4] = {(const float*)d_in[4], (const float*)d_in[5],
                        (const float*)d_in[6], (const float*)d_in[7]};
  const float* ct_w[4] = {(const float*)d_in[8], (const float*)d_in[10],
                          (const float*)d_in[12], (const float*)d_in[14]};
  const float* ct_b[4] = {(const float*)d_in[9], (const float*)d_in[11],
                          (const float*)d_in[13], (const float*)d_in[15]};
  const float* loc_cw = (const float*)d_in[16];
  const float* loc_cb = (const float*)d_in[17];
  const float* loc_g  = (const float*)d_in[18];
  const float* loc_bt = (const float*)d_in[19];
  const float* loc_w1 = (const float*)d_in[20];
  const float* loc_b1 = (const float*)d_in[21];
  const float* loc_w2 = (const float*)d_in[22];
  const float* loc_b2 = (const float*)d_in[23];
  const float* sem_cw = (const float*)d_in[24];
  const float* sem_cb = (const float*)d_in[25];
  const float* sem_g  = (const float*)d_in[26];
  const float* sem_bt = (const float*)d_in[27];
  const float* sem_w1 = (const float*)d_in[28];
  const float* sem_b1 = (const float*)d_in[29];
  const float* sem_w2 = (const float*)d_in[30];
  const float* sem_b2 = (const float*)d_in[31];

  static const int Hs[4]  = {200, 100, 50, 25};
  static const int OHs[4] = {100, 50, 25, 13};
  static const int CIN[4] = {256, 512, 1024, 2048};

  float* Wb = (float*)d_ws;
  size_t off = 0;
  auto alloc = [&](size_t n) { float* p = Wb + off; off += (n + 63) & ~(size_t)63; return p; };

  float* tb[4];
  for (int s = 0; s < 4; s++) tb[s] = alloc((size_t)2 * 256 * Hs[s] * Hs[s]);
  float* wt3[2];
  wt3[0] = alloc(256 * 256 * 9);
  wt3[1] = alloc(256 * 256 * 9);
  float* wt1[4];
  for (int s = 0; s < 4; s++) wt1[s] = alloc((size_t)CIN[s] * 256);
  float* y[16];
  for (int p = 0; p < 16; p++) {
    int s = p & 3;
    y[p] = alloc((size_t)2 * 256 * OHs[s] * OHs[s]);
  }
  float* mv  = alloc(16 * 512);
  float* fea = alloc(16 * 512);
  float* enc = alloc(16 * 512);

  // 1. weight transposes
  tw3_k<<<dim3(1024), dim3(256), 0, stream>>>(loc_cw, sem_cw, wt3[0], wt3[1]);
  {
    TW1Args t;
    for (int s = 0; s < 4; s++) { t.w[s] = ct_w[s]; t.wt[s] = wt1[s]; t.cin[s] = CIN[s]; }
    tw1_k<<<dim3(512, 4), dim3(256), 0, stream>>>(t);
  }

  // 2. conv1x1 -> tb
  for (int s = 0; s < 4; s++) {
    int HW = Hs[s] * Hs[s];
    Conv1Args a;
    a.x = xb[s]; a.wt = wt1[s]; a.bias = ct_b[s]; a.out = tb[s]; a.Cin = CIN[s]; a.HW = HW;
    dim3 grid((HW + 127) / 128, 4, 2);
    conv1x1_k<<<grid, dim3(256), 0, stream>>>(a);
  }

  // 3. conv3x3 encoders (4 passes per scale: g0=tb/loc g1=x/loc g2=tb/sem g3=x/sem)
  for (int s = 0; s < 4; s++) {
    Conv3Args a;
    for (int g = 0; g < 4; g++) {
      a.in[g] = (g & 1) ? xs[s] : tb[s];
      a.wt[g] = (g < 2) ? wt3[0] : wt3[1];
      a.cb[g] = (g < 2) ? loc_cb : sem_cb;
      a.out[g] = y[g * 4 + s];
    }
    a.H = Hs[s]; a.W = Hs[s]; a.OH = OHs[s]; a.OW = OHs[s];
    a.n_ow_t = (a.OW + 15) / 16;
    int n_oh_t = (a.OH + 7) / 8;
    dim3 grid(a.n_ow_t * n_oh_t, 4, 8);
    conv3x3_k<<<grid, dim3(256), 0, stream>>>(a);
  }

  // 4. BN stats
  {
    RedArgs r;
    for (int p = 0; p < 16; p++) { r.y[p] = y[p]; r.ohw[p] = OHs[p & 3] * OHs[p & 3]; }
    r.mv = mv;
    bn_reduce_k<<<dim3(256, 16), dim3(256), 0, stream>>>(r);
  }

  // 5. fea
  {
    FeaArgs f;
    for (int p = 0; p < 16; p++) {
      f.y[p] = y[p];
      f.ohw[p] = OHs[p & 3] * OHs[p & 3];
      f.g[p]    = (p < 8) ? loc_g  : sem_g;
      f.beta[p] = (p < 8) ? loc_bt : sem_bt;
    }
    f.mv = mv; f.fea = fea;
    fea_k<<<dim3(256, 32), dim3(256), 0, stream>>>(f);
  }

  // 6. MLPs
  {
    MlpArgs m;
    for (int p = 0; p < 16; p++) {
      m.w1[p] = (p < 8) ? loc_w1 : sem_w1;
      m.b1[p] = (p < 8) ? loc_b1 : sem_b1;
      m.w2[p] = (p < 8) ? loc_w2 : sem_w2;
      m.b2[p] = (p < 8) ? loc_b2 : sem_b2;
    }
    m.fea = fea; m.enc = enc;
    mlp_k<<<dim3(16), dim3(512), 0, stream>>>(m);
  }

  // 7. loss
  loss_k<<<dim3(1), dim3(256), 0, stream>>>(enc, (float*)d_out);
}

// Round 2
// 1779.578 us; speedup vs baseline: 2.8099x; 2.8099x over previous
//
#include <hip/hip_runtime.h>
#include <math.h>

// Contrastive loss forward.
// conv3x3 encoders now run on bf16 MFMA (hi/lo split, 3 products = fp32-ish
// precision). Inputs to conv3 are pre-transposed to NHWC bf16 hi/lo; weights
// to [set][k][cib][co][cic] bf16 hi/lo. y stored bf16 (channel-padded to x8).

#define DEV static __device__ __forceinline__

typedef short bh8 __attribute__((ext_vector_type(8)));
typedef float fx16 __attribute__((ext_vector_type(16)));

DEV float leaky_f(float x) { return x > 0.f ? x : 0.1f * x; }
DEV float4 ld4(const float* p) { return *(const float4*)p; }

DEV ushort f2bf(float x) {
  uint u = __float_as_uint(x);
  uint r = (u + 0x7fffu + ((u >> 16) & 1u)) >> 16;
  return (ushort)r;
}
DEV float bf2f(ushort h) { return __uint_as_float(((uint)h) << 16); }
DEV void split2(float x, ushort& h, ushort& l) {
  ushort hh = f2bf(x);
  h = hh;
  l = f2bf(x - bf2f(hh));
}

DEV fx16 mfma32(bh8 a, bh8 b, fx16 c) {
  return __builtin_amdgcn_mfma_f32_32x32x16_bf16(a, b, c, 0, 0, 0);
}

// ---------------- conv1x1 weight transpose (fp32, [ci][co]) -----------------
struct TW1Args { const float* w[4]; float* wt[4]; int cin[4]; };
__global__ void tw1_k(TW1Args a) {
  int s = blockIdx.y;
  int cin = a.cin[s];
  int N = cin * 256;
  const float* w = a.w[s];
  float* wt = a.wt[s];
  for (int idx = blockIdx.x * 256 + threadIdx.x; idx < N; idx += gridDim.x * 256) {
    int co = idx & 255, ci = idx >> 8;
    wt[idx] = w[co * cin + ci];
  }
}

// ---------------- conv3x3 weight prep: fp32 -> bf16 hi/lo, MFMA layout ------
// W3[set][k][cib][co][cic], ci = cib*16+cic
__global__ void w3prep_k(const float* __restrict__ loc, const float* __restrict__ sem,
                         ushort* __restrict__ WH, ushort* __restrict__ WL) {
  const int N = 2 * 9 * 16 * 256 * 16;
  for (int o = blockIdx.x * 256 + threadIdx.x; o < N; o += gridDim.x * 256) {
    int set = o / 589824;
    int r = o - set * 589824;
    int k = r / 65536;
    int r2 = r - k * 65536;
    int cib = r2 / 4096;
    int r3 = r2 - cib * 4096;
    int co = r3 >> 4, cic = r3 & 15;
    float w = (set ? sem : loc)[(co * 256 + cib * 16 + cic) * 9 + k];
    ushort h, l;
    split2(w, h, l);
    WH[o] = h;
    WL[o] = l;
  }
}

// ---------------- xs transpose+split: NCHW fp32 -> NHWC bf16 hi/lo ----------
struct XprepArgs { const float* x; ushort* oH; ushort* oL; int HW; };
__global__ __launch_bounds__(256) void xprep_k(XprepArgs a) {
  __shared__ float sT[32][65];
  const int tid = threadIdx.x;
  const int p0 = blockIdx.x * 64, c0 = blockIdx.y * 32, b = blockIdx.z;
  const float* xp = a.x + ((size_t)b * 256 + c0) * a.HW;
  for (int e = tid; e < 32 * 64; e += 256) {
    int ci = e >> 6, px = e & 63;
    int p = p0 + px;
    sT[ci][px] = (p < a.HW) ? xp[(size_t)ci * a.HW + p] : 0.f;
  }
  __syncthreads();
  const int px = tid >> 2, c8 = (tid & 3) * 8;
  if (p0 + px < a.HW) {
    bh8 hv, lv;
#pragma unroll
    for (int i = 0; i < 8; i++) {
      ushort h, l;
      split2(sT[c8 + i][px], h, l);
      hv[i] = (short)h;
      lv[i] = (short)l;
    }
    size_t o = ((size_t)b * a.HW + p0 + px) * 256 + c0 + c8;
    *(bh8*)(a.oH + o) = hv;
    *(bh8*)(a.oL + o) = lv;
  }
}

// ---------------- conv1x1: fp32 compute, NHWC bf16 hi/lo output -------------
struct Conv1Args { const float* x; const float* wt; const float* bias;
                   ushort* outH; ushort* outL; int Cin; int HW; };
__global__ __launch_bounds__(256) void conv1x1_k(Conv1Args a) {
  __shared__ float sX[8][128];
  __shared__ float sW[8][64];
  const int tid = threadIdx.x;
  const int p0 = blockIdx.x * 128;
  const int co0 = blockIdx.y * 64;
  const int b = blockIdx.z;
  const float* x = a.x + (size_t)b * a.Cin * a.HW;
  const int cog = tid >> 4;
  const int posg = tid & 15;
  const bool aligned4 = ((a.HW & 3) == 0);

  float acc[4][8];
#pragma unroll
  for (int i = 0; i < 4; i++)
#pragma unroll
    for (int j = 0; j < 8; j++) acc[i][j] = 0.f;

  for (int ci0 = 0; ci0 < a.Cin; ci0 += 8) {
    __syncthreads();
    {
      int ci = tid >> 5, c4 = tid & 31;
      int p = p0 + c4 * 4;
      const float* src = x + (size_t)(ci0 + ci) * a.HW;
      float4 v = make_float4(0.f, 0.f, 0.f, 0.f);
      if (aligned4 && p + 3 < a.HW) {
        v = ld4(src + p);
      } else {
        float t0 = (p + 0 < a.HW) ? src[p + 0] : 0.f;
        float t1 = (p + 1 < a.HW) ? src[p + 1] : 0.f;
        float t2 = (p + 2 < a.HW) ? src[p + 2] : 0.f;
        float t3 = (p + 3 < a.HW) ? src[p + 3] : 0.f;
        v = make_float4(t0, t1, t2, t3);
      }
      *(float4*)&sX[ci][c4 * 4] = v;
    }
    if (tid < 128) {
      int ci = tid >> 4, c4 = tid & 15;
      *(float4*)&sW[ci][c4 * 4] = ld4(&a.wt[(size_t)(ci0 + ci) * 256 + co0 + c4 * 4]);
    }
    __syncthreads();
#pragma unroll
    for (int ci = 0; ci < 8; ci++) {
      float4 wv = *(float4*)&sW[ci][cog * 4];
      float4 x0 = *(float4*)&sX[ci][posg * 8];
      float4 x1 = *(float4*)&sX[ci][posg * 8 + 4];
      float xr[8] = {x0.x, x0.y, x0.z, x0.w, x1.x, x1.y, x1.z, x1.w};
#pragma unroll
      for (int j = 0; j < 8; j++) {
        acc[0][j] += wv.x * xr[j];
        acc[1][j] += wv.y * xr[j];
        acc[2][j] += wv.z * xr[j];
        acc[3][j] += wv.w * xr[j];
      }
    }
  }
  float4 bv = ld4(&a.bias[co0 + cog * 4]);
  float bias[4] = {bv.x, bv.y, bv.z, bv.w};
#pragma unroll
  for (int j = 0; j < 8; j++) {
    int pix = p0 + posg * 8 + j;
    if (pix < a.HW) {
      ushort hv[4], lv[4];
#pragma unroll
      for (int i = 0; i < 4; i++) split2(acc[i][j] + bias[i], hv[i], lv[i]);
      size_t o = ((size_t)b * a.HW + pix) * 256 + co0 + cog * 4;
      ushort4 h4; h4.x = hv[0]; h4.y = hv[1]; h4.z = hv[2]; h4.w = hv[3];
      ushort4 l4; l4.x = lv[0]; l4.y = lv[1]; l4.z = lv[2]; l4.w = lv[3];
      *(ushort4*)(a.outH + o) = h4;
      *(ushort4*)(a.outL + o) = l4;
    }
  }
}

// ---------------- conv3x3 s2 p1 via bf16x3 MFMA, all scales/passes ----------
struct C3Args {
  const ushort* inH[2][4];   // [src: 0=tb 1=x][scale]
  const ushort* inL[2][4];
  const ushort* w3H; const ushort* w3L;  // [set][9][16][256][16]
  const float* cb[2];
  ushort* y[16];
  int H[4], OH[4], OW[4], OHWp[4], nOwT[4];
  int cumTiles[5];
};
__global__ __launch_bounds__(256, 2) void conv3_k(C3Args a) {
  const int tx = blockIdx.x;
  int s = 0;
  while (tx >= a.cumTiles[s + 1]) s++;
  const int tloc = tx - a.cumTiles[s];
  const int pass = blockIdx.y, b = blockIdx.z;
  const int H = a.H[s], OH = a.OH[s], OW = a.OW[s], OHWp = a.OHWp[s];
  const int nOwT = a.nOwT[s];
  const int toh = tloc / nOwT, tow = tloc - toh * nOwT;
  const int oh0 = toh * 8, ow0 = tow * 16;
  const int src = pass & 1, set = pass >> 1;
  const ushort* XH = a.inH[src][s] + (size_t)b * H * H * 256;
  const ushort* XL = a.inL[src][s] + (size_t)b * H * H * 256;
  const ushort* WH = a.w3H + (size_t)set * 9 * 16 * 256 * 16;
  const ushort* WL = a.w3L + (size_t)set * 9 * 16 * 256 * 16;
  ushort* yout = a.y[pass * 4 + s] + (size_t)b * 256 * OHWp;

  __shared__ ushort sB[2][561 * 16];

  const int tid = threadIdx.x;
  const int wid = tid >> 6, lane = tid & 63;
  const int coH = wid >> 1, ns = wid & 1;
  const int n32 = lane & 31, half = lane >> 5;
  const int owL = n32 & 15, doh = n32 >> 4;
  const int ihBase = 2 * oh0 - 1, iwBase = 2 * ow0 - 1;
  const int wlane = (coH * 128 + n32) * 16 + half * 8;

  fx16 zz;
#pragma unroll
  for (int e = 0; e < 16; e++) zz[e] = 0.f;
  fx16 acc[4][2];
#pragma unroll
  for (int mf = 0; mf < 4; mf++)
#pragma unroll
    for (int nf = 0; nf < 2; nf++) acc[mf][nf] = zz;

  for (int cib = 0; cib < 16; cib++) {
    const int ci0 = cib * 16;
    __syncthreads();
    for (int t = 0; t < 9; t++) {
      int S = tid + t * 256;
      if (S < 2244) {
        int sp = S / 1122;
        int r = S - sp * 1122;
        int p = r >> 1, h = r & 1;
        int ihr = p / 33, se = p - ihr * 33;
        int iwr = (se < 17) ? 2 * se : 2 * (se - 17) + 1;
        int ih = ihBase + ihr, iw = iwBase + iwr;
        uint4 v = {0u, 0u, 0u, 0u};
        if (ih >= 0 && ih < H && iw >= 0 && iw < H) {
          const ushort* sptr = (sp ? XL : XH) + ((size_t)(ih * H + iw)) * 256 + ci0 + h * 8;
          v = *(const uint4*)sptr;
        }
        int a16 = (p * 2 + h) ^ ((se >> 2) & 1);
        *(uint4*)&sB[sp][a16 * 8] = v;
      }
    }
    __syncthreads();
    for (int kh = 0; kh < 3; kh++) {
      for (int kw = 0; kw < 3; kw++) {
        const int k = kh * 3 + kw;
        const size_t wo = ((size_t)k * 16 + cib) * 4096 + wlane;
        bh8 ah[4], al[4];
#pragma unroll
        for (int mf = 0; mf < 4; mf++) {
          ah[mf] = *(const bh8*)(WH + wo + mf * 512);
          al[mf] = *(const bh8*)(WL + wo + mf * 512);
        }
#pragma unroll
        for (int nf = 0; nf < 2; nf++) {
          int ohL = ns * 4 + nf * 2 + doh;
          int ihr = 2 * ohL + kh;
          int se = (kw == 1) ? 17 + owL : owL + (kw >> 1);
          int p = ihr * 33 + se;
          int a16 = (p * 2 + half) ^ ((se >> 2) & 1);
          bh8 bhf = *(const bh8*)&sB[0][a16 * 8];
          bh8 blf = *(const bh8*)&sB[1][a16 * 8];
#pragma unroll
          for (int mf = 0; mf < 4; mf++) {
            acc[mf][nf] = mfma32(ah[mf], bhf, acc[mf][nf]);
            acc[mf][nf] = mfma32(ah[mf], blf, acc[mf][nf]);
            acc[mf][nf] = mfma32(al[mf], bhf, acc[mf][nf]);
          }
        }
      }
    }
  }
  const float* cb = a.cb[set];
  const int ow = ow0 + owL;
#pragma unroll
  for (int mf = 0; mf < 4; mf++) {
#pragma unroll
    for (int nf = 0; nf < 2; nf++) {
      int oh = oh0 + ns * 4 + nf * 2 + doh;
      if (oh < OH && ow < OW) {
#pragma unroll
        for (int reg = 0; reg < 16; reg++) {
          int row = (reg & 3) + 8 * (reg >> 2) + 4 * half;
          int co = coH * 128 + mf * 32 + row;
          float v = acc[mf][nf][reg] + cb[co];
          yout[(size_t)co * OHWp + oh * OW + ow] = f2bf(v);
        }
      }
    }
  }
}

// ---------------- BN stats over bf16 y --------------------------------------
struct RedArgs { const ushort* y[16]; float* mv; int ohw[16]; int ohwp[16]; };
__global__ __launch_bounds__(256) void bn_reduce_k(RedArgs a) {
  const int c = blockIdx.x, p = blockIdx.y;
  const int ohwp = a.ohwp[p];
  const int n8 = ohwp >> 3;
  float s = 0.f, s2 = 0.f;
  for (int b = 0; b < 2; b++) {
    const ushort* base = a.y[p] + (size_t)(b * 256 + c) * ohwp;
    for (int i = threadIdx.x; i < n8; i += 256) {
      uint4 v = *(const uint4*)(base + i * 8);
      uint ua[4] = {v.x, v.y, v.z, v.w};
#pragma unroll
      for (int w = 0; w < 4; w++) {
        float f0 = bf2f((ushort)(ua[w] & 0xffffu));
        float f1 = bf2f((ushort)(ua[w] >> 16));
        s += f0 + f1;
        s2 += f0 * f0 + f1 * f1;
      }
    }
  }
  __shared__ float rs[4], rs2[4];
  for (int off = 32; off > 0; off >>= 1) { s += __shfl_down(s, off); s2 += __shfl_down(s2, off); }
  int wid = threadIdx.x >> 6, lanei = threadIdx.x & 63;
  if (lanei == 0) { rs[wid] = s; rs2[wid] = s2; }
  __syncthreads();
  if (threadIdx.x == 0) {
    float S = 0.f, S2 = 0.f;
    for (int w = 0; w < 4; w++) { S += rs[w]; S2 += rs2[w]; }
    float n = (float)(2 * a.ohw[p]);
    float m = S / n;
    a.mv[p * 512 + c] = m;
    a.mv[p * 512 + 256 + c] = S2 / n - m * m;
  }
}

// ---------------- fea[p,b,c] = mean_spatial( leaky(BN(y)) ) ------------------
struct FeaArgs { const ushort* y[16]; const float* g[16]; const float* beta[16];
                 const float* mv; float* fea; int ohw[16]; int ohwp[16]; };
__global__ __launch_bounds__(256) void fea_k(FeaArgs a) {
  const int c = blockIdx.x;
  const int z = blockIdx.y;
  const int p = z >> 1, b = z & 1;
  const int ohw = a.ohw[p], ohwp = a.ohwp[p];
  const int n8 = ohwp >> 3;
  float m = a.mv[p * 512 + c], v = a.mv[p * 512 + 256 + c];
  float rsq = 1.0f / sqrtf(v + 1e-5f);
  float gg = a.g[p][c] * rsq;
  float bb = a.beta[p][c] - m * gg;
  const ushort* base = a.y[p] + (size_t)(b * 256 + c) * ohwp;
  float s = 0.f;
  for (int i = threadIdx.x; i < n8; i += 256) {
    uint4 vv = *(const uint4*)(base + i * 8);
    uint ua[4] = {vv.x, vv.y, vv.z, vv.w};
#pragma unroll
    for (int w = 0; w < 4; w++) {
      int e = i * 8 + w * 2;
      float f0 = bf2f((ushort)(ua[w] & 0xffffu));
      float f1 = bf2f((ushort)(ua[w] >> 16));
      if (e < ohw) s += leaky_f(f0 * gg + bb);
      if (e + 1 < ohw) s += leaky_f(f1 * gg + bb);
    }
  }
  __shared__ float rsm[4];
  for (int off = 32; off > 0; off >>= 1) s += __shfl_down(s, off);
  int wid = threadIdx.x >> 6, lanei = threadIdx.x & 63;
  if (lanei == 0) rsm[wid] = s;
  __syncthreads();
  if (threadIdx.x == 0) {
    float S = rsm[0] + rsm[1] + rsm[2] + rsm[3];
    a.fea[((size_t)p * 2 + b) * 256 + c] = S / (float)ohw;
  }
}

// ---------------- 2-layer MLP per pass ---------------------------------------
struct MlpArgs { const float* fea; const float* w1[16]; const float* b1[16];
                 const float* w2[16]; const float* b2[16]; float* enc; };
__global__ __launch_bounds__(512) void mlp_k(MlpArgs a) {
  const int p = blockIdx.x;
  const int t = threadIdx.x;
  const int b = t >> 8, co = t & 255;
  __shared__ float sfea[2][256];
  __shared__ float sh[2][256];
  sfea[b][co] = a.fea[((size_t)p * 2 + b) * 256 + co];
  __syncthreads();
  {
    const float* w1 = a.w1[p] + (size_t)co * 256;
    float s = a.b1[p][co];
    for (int ci = 0; ci < 256; ci += 4) {
      float4 wv = ld4(&w1[ci]);
      s += wv.x * sfea[b][ci] + wv.y * sfea[b][ci + 1] + wv.z * sfea[b][ci + 2] + wv.w * sfea[b][ci + 3];
    }
    sh[b][co] = leaky_f(s);
  }
  __syncthreads();
  {
    const float* w2 = a.w2[p] + (size_t)co * 256;
    float s = a.b2[p][co];
    for (int ci = 0; ci < 256; ci += 4) {
      float4 wv = ld4(&w2[ci]);
      s += wv.x * sh[b][ci] + wv.y * sh[b][ci + 1] + wv.z * sh[b][ci + 2] + wv.w * sh[b][ci + 3];
    }
    a.enc[((size_t)p * 2 + b) * 256 + co] = s;
  }
}

// ---------------- final loss -------------------------------------------------
__global__ __launch_bounds__(256) void loss_k(const float* __restrict__ enc, float* __restrict__ out) {
  __shared__ float nv[32][256];
  __shared__ float norms[32];
  __shared__ float sE[4][64];
  const int tid = threadIdx.x;
  if (tid < 32) {
    const float* v = enc + (size_t)tid * 256;
    float s = 0.f;
    for (int i = 0; i < 256; i++) s += v[i] * v[i];
    norms[tid] = fmaxf(sqrtf(s), 1e-12f);
  }
  __syncthreads();
  for (int idx = tid; idx < 8192; idx += 256) {
    int vi = idx >> 8, c = idx & 255;
    nv[vi][c] = enc[idx] / norms[vi];
  }
  __syncthreads();
  {
    int m = tid >> 6, e = tid & 63;
    int i = e >> 4, b = (e >> 3) & 1, k = (e >> 1) & 3, l = e & 1;
    int ga = (m < 2) ? 1 : 3;
    int gb = (m == 0) ? 1 : (m == 1) ? 0 : (m == 2) ? 3 : 2;
    const float* va = nv[ga * 8 + i * 2 + b];
    const float* vb = nv[gb * 8 + k * 2 + l];
    float d = 0.f;
    for (int c = 0; c < 256; c++) d += va[c] * vb[c];
    sE[m][e] = expf(d * 2.0f);
  }
  __syncthreads();
  if (tid == 0) {
    float geo = 0.f;
    for (int i = 0; i < 4; i++)
      for (int b = 0; b < 2; b++) {
        float num = sE[1][i * 16 + b * 8 + i * 2 + b];
        float den = num;
        for (int k = 0; k < 4; k++)
          for (int l = 0; l < 2; l++)
            if (k != i && l != b)
              den += sE[0][i * 16 + b * 8 + k * 2 + l] + sE[1][i * 16 + b * 8 + k * 2 + l];
        geo -= logf(num / den);
      }
    out[0] = geo;
    float sem = 0.f;
    for (int i = 0; i < 3; i++)
      for (int b = 0; b < 2; b++) {
        float num = sE[2][i * 16 + b * 8 + (i + 1) * 2 + b];
        float den = num;
        for (int k = 0; k < 4; k++)
          for (int l = 0; l < 2; l++)
            if (l != b)
              den += sE[2][i * 16 + b * 8 + k * 2 + l] + sE[3][i * 16 + b * 8 + k * 2 + l];
        sem -= logf(num / den);
      }
    out[1] = sem;
  }
}

// ---------------- host launcher ---------------------------------------------
extern "C" void kernel_launch(void* const* d_in, const int* in_sizes, int n_in,
                              void* d_out, int out_size, void* d_ws, size_t ws_size,
                              hipStream_t stream) {
  (void)in_sizes; (void)n_in; (void)out_size; (void)ws_size;
  const float* xb[4] = {(const float*)d_in[0], (const float*)d_in[1],
                        (const float*)d_in[2], (const float*)d_in[3]};
  const float* xs[4] = {(const float*)d_in[4], (const float*)d_in[5],
                        (const float*)d_in[6], (const float*)d_in[7]};
  const float* ct_w[4] = {(const float*)d_in[8], (const float*)d_in[10],
                          (const float*)d_in[12], (const float*)d_in[14]};
  const float* ct_b[4] = {(const float*)d_in[9], (const float*)d_in[11],
                          (const float*)d_in[13], (const float*)d_in[15]};
  const float* loc_cw = (const float*)d_in[16];
  const float* loc_cb = (const float*)d_in[17];
  const float* loc_g  = (const float*)d_in[18];
  const float* loc_bt = (const float*)d_in[19];
  const float* loc_w1 = (const float*)d_in[20];
  const float* loc_b1 = (const float*)d_in[21];
  const float* loc_w2 = (const float*)d_in[22];
  const float* loc_b2 = (const float*)d_in[23];
  const float* sem_cw = (const float*)d_in[24];
  const float* sem_cb = (const float*)d_in[25];
  const float* sem_g  = (const float*)d_in[26];
  const float* sem_bt = (const float*)d_in[27];
  const float* sem_w1 = (const float*)d_in[28];
  const float* sem_b1 = (const float*)d_in[29];
  const float* sem_w2 = (const float*)d_in[30];
  const float* sem_b2 = (const float*)d_in[31];

  static const int Hs[4]   = {200, 100, 50, 25};
  static const int OHs[4]  = {100, 50, 25, 13};
  static const int OHWp[4] = {10000, 2504, 632, 176};
  static const int CIN[4]  = {256, 512, 1024, 2048};
  static const int nOwT[4] = {7, 4, 2, 1};
  static const int nOhT[4] = {13, 7, 4, 2};
  static const size_t preHW[4] = {0, 40000, 50000, 52500};  // prefix of HW

  char* base = (char*)d_ws;
  size_t off = 0;
  auto alloc = [&](size_t bytes) -> char* {
    char* p = base + off;
    off = (off + bytes + 255) & ~(size_t)255;
    return p;
  };

  float* wt1[4];
  for (int s = 0; s < 4; s++) wt1[s] = (float*)alloc((size_t)CIN[s] * 256 * 4);
  ushort* W3H = (ushort*)alloc((size_t)2 * 9 * 16 * 256 * 16 * 2);
  ushort* W3L = (ushort*)alloc((size_t)2 * 9 * 16 * 256 * 16 * 2);
  ushort* tbH = (ushort*)alloc((size_t)2 * 53125 * 256 * 2);
  ushort* tbL = (ushort*)alloc((size_t)2 * 53125 * 256 * 2);
  ushort* xH  = (ushort*)alloc((size_t)2 * 53125 * 256 * 2);
  ushort* xL  = (ushort*)alloc((size_t)2 * 53125 * 256 * 2);
  size_t ytot = 0;
  for (int p = 0; p < 16; p++) ytot += (size_t)2 * 256 * OHWp[p & 3] * 2;
  char* yAll = alloc(ytot);
  ushort* y[16];
  {
    size_t c = 0;
    for (int p = 0; p < 16; p++) {
      y[p] = (ushort*)(yAll + c);
      c += (size_t)2 * 256 * OHWp[p & 3] * 2;
    }
  }
  float* mv  = (float*)alloc(16 * 512 * 4);
  float* fea = (float*)alloc(16 * 512 * 4);
  float* enc = (float*)alloc(16 * 512 * 4);

  // 1. weight preps
  {
    TW1Args t;
    for (int s = 0; s < 4; s++) { t.w[s] = ct_w[s]; t.wt[s] = wt1[s]; t.cin[s] = CIN[s]; }
    tw1_k<<<dim3(512, 4), dim3(256), 0, stream>>>(t);
  }
  w3prep_k<<<dim3(2048), dim3(256), 0, stream>>>(loc_cw, sem_cw, W3H, W3L);

  // 2. xs -> NHWC bf16 hi/lo
  for (int s = 0; s < 4; s++) {
    int HW = Hs[s] * Hs[s];
    XprepArgs xa;
    xa.x = xs[s];
    xa.oH = xH + preHW[s] * 512;
    xa.oL = xL + preHW[s] * 512;
    xa.HW = HW;
    xprep_k<<<dim3((HW + 63) / 64, 8, 2), dim3(256), 0, stream>>>(xa);
  }

  // 3. conv1x1 -> tb NHWC bf16 hi/lo
  for (int s = 0; s < 4; s++) {
    int HW = Hs[s] * Hs[s];
    Conv1Args a;
    a.x = xb[s]; a.wt = wt1[s]; a.bias = ct_b[s];
    a.outH = tbH + preHW[s] * 512;
    a.outL = tbL + preHW[s] * 512;
    a.Cin = CIN[s]; a.HW = HW;
    conv1x1_k<<<dim3((HW + 127) / 128, 4, 2), dim3(256), 0, stream>>>(a);
  }

  // 4. zero y (pads must be zero for BN sums)
  hipMemsetAsync(yAll, 0, ytot, stream);

  // 5. conv3x3 encoders, all scales/passes/batches in one dispatch
  {
    C3Args a;
    for (int s = 0; s < 4; s++) {
      a.inH[0][s] = tbH + preHW[s] * 512;
      a.inL[0][s] = tbL + preHW[s] * 512;
      a.inH[1][s] = xH + preHW[s] * 512;
      a.inL[1][s] = xL + preHW[s] * 512;
      a.H[s] = Hs[s]; a.OH[s] = OHs[s]; a.OW[s] = OHs[s];
      a.OHWp[s] = OHWp[s]; a.nOwT[s] = nOwT[s];
    }
    a.w3H = W3H; a.w3L = W3L;
    a.cb[0] = loc_cb; a.cb[1] = sem_cb;
    for (int p = 0; p < 16; p++) a.y[p] = y[p];
    a.cumTiles[0] = 0;
    for (int s = 0; s < 4; s++) a.cumTiles[s + 1] = a.cumTiles[s] + nOwT[s] * nOhT[s];
    conv3_k<<<dim3(a.cumTiles[4], 4, 2), dim3(256), 0, stream>>>(a);
  }

  // 6. BN stats
  {
    RedArgs r;
    for (int p = 0; p < 16; p++) {
      r.y[p] = y[p];
      r.ohw[p] = OHs[p & 3] * OHs[p & 3];
      r.ohwp[p] = OHWp[p & 3];
    }
    r.mv = mv;
    bn_reduce_k<<<dim3(256, 16), dim3(256), 0, stream>>>(r);
  }

  // 7. fea
  {
    FeaArgs f;
    for (int p = 0; p < 16; p++) {
      f.y[p] = y[p];
      f.ohw[p] = OHs[p & 3] * OHs[p & 3];
      f.ohwp[p] = OHWp[p & 3];
      f.g[p]    = (p < 8) ? loc_g  : sem_g;
      f.beta[p] = (p < 8) ? loc_bt : sem_bt;
    }
    f.mv = mv; f.fea = fea;
    fea_k<<<dim3(256, 32), dim3(256), 0, stream>>>(f);
  }

  // 8. MLPs
  {
    MlpArgs m;
    for (int p = 0; p < 16; p++) {
      m.w1[p] = (p < 8) ? loc_w1 : sem_w1;
      m.b1[p] = (p < 8) ? loc_b1 : sem_b1;
      m.w2[p] = (p < 8) ? loc_w2 : sem_w2;
      m.b2[p] = (p < 8) ? loc_b2 : sem_b2;
    }
    m.fea = fea; m.enc = enc;
    mlp_k<<<dim3(16), dim3(512), 0, stream>>>(m);
  }

  // 9. loss
  loss_k<<<dim3(1), dim3(256), 0, stream>>>(enc, (float*)d_out);
}

// Round 3
// 962.133 us; speedup vs baseline: 5.1973x; 1.8496x over previous
//
#include <hip/hip_runtime.h>
#include <math.h>

// Contrastive loss forward, round 3.
// - conv3x3 + conv1x1 both on fp16 MFMA, 2 products (x fp16 single, w = wh+wl fp16).
// - Double-buffered LDS with register prefetch (stage overlaps MFMA, 1 barrier/iter).
// - All inputs pre-transposed to NHWC fp16; y stored bf16 NCHW-padded.

#define DEV static __device__ __forceinline__

typedef _Float16 f16x8 __attribute__((ext_vector_type(8)));
typedef _Float16 f16x4 __attribute__((ext_vector_type(4)));
typedef float fx16 __attribute__((ext_vector_type(16)));

DEV float leaky_f(float x) { return x > 0.f ? x : 0.1f * x; }
DEV float4 ld4(const float* p) { return *(const float4*)p; }

DEV ushort f2bf(float x) {
  uint u = __float_as_uint(x);
  uint r = (u + 0x7fffu + ((u >> 16) & 1u)) >> 16;
  return (ushort)r;
}
DEV float bf2f(ushort h) { return __uint_as_float(((uint)h) << 16); }

DEV fx16 mfma16(f16x8 a, f16x8 b, fx16 c) {
  return __builtin_amdgcn_mfma_f32_32x32x16_f16(a, b, c, 0, 0, 0);
}

// ---------------- conv1x1 weight prep: [s][cib][co][cic] fp16 hi/lo ---------
struct W1PArgs { const float* w[4]; _Float16* oH[4]; _Float16* oL[4]; int Cin[4]; };
__global__ void w1prep_k(W1PArgs a) {
  int s = blockIdx.y;
  int Cin = a.Cin[s];
  int N = Cin * 256;
  for (int idx = blockIdx.x * 256 + threadIdx.x; idx < N; idx += gridDim.x * 256) {
    int cic = idx & 15, co = (idx >> 4) & 255, cib = idx >> 12;
    float w = a.w[s][co * Cin + cib * 16 + cic];
    _Float16 h = (_Float16)w;
    _Float16 l = (_Float16)(w - (float)h);
    a.oH[s][idx] = h;
    a.oL[s][idx] = l;
  }
}

// ---------------- conv3x3 weight prep: [set][k][cib][co][cic] fp16 hi/lo ----
__global__ void w3prep_k(const float* __restrict__ loc, const float* __restrict__ sem,
                         _Float16* __restrict__ WH, _Float16* __restrict__ WL) {
  const int N = 2 * 9 * 16 * 256 * 16;
  for (int o = blockIdx.x * 256 + threadIdx.x; o < N; o += gridDim.x * 256) {
    int set = o / 589824;
    int r = o - set * 589824;
    int k = r / 65536;
    int r2 = r - k * 65536;
    int cib = r2 / 4096;
    int r3 = r2 - cib * 4096;
    int co = r3 >> 4, cic = r3 & 15;
    float w = (set ? sem : loc)[(co * 256 + cib * 16 + cic) * 9 + k];
    _Float16 h = (_Float16)w;
    _Float16 l = (_Float16)(w - (float)h);
    WH[o] = h;
    WL[o] = l;
  }
}

// ---------------- NCHW fp32 -> NHWC fp16 transpose (any Cin) ----------------
__global__ __launch_bounds__(256) void xT_k(const float* __restrict__ x, _Float16* __restrict__ o,
                                            int HW, int Cin) {
  __shared__ float sT[32][65];
  const int tid = threadIdx.x;
  const int p0 = blockIdx.x * 64, c0 = blockIdx.y * 32, b = blockIdx.z;
  const float* xp = x + ((size_t)b * Cin + c0) * HW;
  for (int e = tid; e < 32 * 64; e += 256) {
    int ci = e >> 6, px = e & 63;
    int p = p0 + px;
    sT[ci][px] = (p < HW) ? xp[(size_t)ci * HW + p] : 0.f;
  }
  __syncthreads();
  const int px = tid >> 2, c8 = (tid & 3) * 8;
  int p = p0 + px;
  if (p < HW) {
    f16x8 v;
#pragma unroll
    for (int i = 0; i < 8; i++) v[i] = (_Float16)sT[c8 + i][px];
    *(f16x8*)(o + ((size_t)b * HW + p) * Cin + c0 + c8) = v;
  }
}

// ---------------- conv1x1 as MFMA GEMM (256co x 128pos tile) ----------------
struct G1Args {
  const _Float16* x[4];                 // NHWC fp16 [b][p][Cin]
  const _Float16* wH[4]; const _Float16* wL[4];  // [cib][co][cic]
  const float* bias[4];
  _Float16* out[4];                     // NHWC fp16 [b][p][256]
  int HW[4], Cin[4];
  int cumT[5];
};
__global__ __launch_bounds__(256, 2) void g1x1_k(G1Args a) {
  const int bx = blockIdx.x;
  int s = 0;
  while (bx >= a.cumT[s + 1]) s++;
  const int p0 = (bx - a.cumT[s]) * 128;
  const int b = blockIdx.z;
  const int HW = a.HW[s], Cin = a.Cin[s];
  const _Float16* X = a.x[s] + (size_t)b * HW * Cin;
  const _Float16* WH = a.wH[s];
  const _Float16* WL = a.wL[s];

  __shared__ _Float16 sX[2][128 * 16];
  const int tid = threadIdx.x;
  const int lane = tid & 63, wid = tid >> 6;
  const int coH = wid >> 1, ns = wid & 1;
  const int n32 = lane & 31, half = lane >> 5;

  const int posL = tid >> 1, hh = tid & 1;
  const int sa = (tid ^ ((tid >> 3) & 1)) * 8;
  const int pos = p0 + posL;
  const bool inb = pos < HW;
  const _Float16* src = X + (size_t)pos * Cin + hh * 8;

  fx16 zz;
#pragma unroll
  for (int e = 0; e < 16; e++) zz[e] = 0.f;
  fx16 acc[4][2];
#pragma unroll
  for (int mf = 0; mf < 4; mf++)
#pragma unroll
    for (int nf = 0; nf < 2; nf++) acc[mf][nf] = zz;

  const int nCib = Cin >> 4;
  uint4 z4 = {0u, 0u, 0u, 0u};
  uint4 rv = inb ? *(const uint4*)src : z4;
  *(uint4*)&sX[0][sa] = rv;
  __syncthreads();
  int buf = 0;
  for (int cib = 0; cib < nCib; cib++) {
    if (cib + 1 < nCib) rv = inb ? *(const uint4*)(src + (size_t)(cib + 1) * 16) : z4;
    const size_t wo = ((size_t)cib * 256 + coH * 128 + n32) * 16 + half * 8;
    f16x8 ah[4], al[4];
#pragma unroll
    for (int mf = 0; mf < 4; mf++) {
      ah[mf] = *(const f16x8*)(WH + wo + mf * 512);
      al[mf] = *(const f16x8*)(WL + wo + mf * 512);
    }
    __builtin_amdgcn_s_setprio(1);
#pragma unroll
    for (int nf = 0; nf < 2; nf++) {
      int idx = (ns * 64 + nf * 32 + n32) * 2 + half;
      int ra = (idx ^ ((idx >> 3) & 1)) * 8;
      f16x8 bf = *(const f16x8*)&sX[buf][ra];
#pragma unroll
      for (int mf = 0; mf < 4; mf++) {
        acc[mf][nf] = mfma16(ah[mf], bf, acc[mf][nf]);
        acc[mf][nf] = mfma16(al[mf], bf, acc[mf][nf]);
      }
    }
    __builtin_amdgcn_s_setprio(0);
    if (cib + 1 < nCib) {
      *(uint4*)&sX[buf ^ 1][sa] = rv;
      __syncthreads();
      buf ^= 1;
    }
  }
  const float* bias = a.bias[s];
  _Float16* O = a.out[s] + (size_t)b * HW * 256;
#pragma unroll
  for (int nf = 0; nf < 2; nf++) {
    int opos = p0 + ns * 64 + nf * 32 + n32;
    if (opos < HW) {
#pragma unroll
      for (int mf = 0; mf < 4; mf++) {
#pragma unroll
        for (int q = 0; q < 4; q++) {
          int co = coH * 128 + mf * 32 + 8 * q + 4 * half;
          f16x4 v;
#pragma unroll
          for (int r = 0; r < 4; r++) v[r] = (_Float16)(acc[mf][nf][q * 4 + r] + bias[co + r]);
          *(f16x4*)(O + (size_t)opos * 256 + co) = v;
        }
      }
    }
  }
}

// ---------------- conv3x3 s2 p1 fp16 MFMA, double-buffered ------------------
struct C3Args {
  const _Float16* in[2][4];   // [src: 0=tb 1=x][scale] NHWC fp16
  const _Float16* w3H; const _Float16* w3L;  // [set][9][16][256][16]
  const float* cb[2];
  ushort* y[16];
  int H[4], OH[4], OW[4], OHWp[4], nOwT[4];
  int cumTiles[5];
};
__global__ __launch_bounds__(256, 2) void conv3_k(C3Args a) {
  const int tx = blockIdx.x;
  int s = 0;
  while (tx >= a.cumTiles[s + 1]) s++;
  const int tloc = tx - a.cumTiles[s];
  const int pass = blockIdx.y, b = blockIdx.z;
  const int H = a.H[s], OH = a.OH[s], OW = a.OW[s], OHWp = a.OHWp[s];
  const int nOwT = a.nOwT[s];
  const int toh = tloc / nOwT, tow = tloc - toh * nOwT;
  const int oh0 = toh * 8, ow0 = tow * 16;
  const int src = pass & 1, set = pass >> 1;
  const _Float16* X = a.in[src][s] + (size_t)b * H * H * 256;
  const _Float16* WH = a.w3H + (size_t)set * 589824;
  const _Float16* WL = a.w3L + (size_t)set * 589824;
  ushort* yout = a.y[pass * 4 + s] + (size_t)b * 256 * OHWp;

  __shared__ _Float16 sB[2][561 * 16];

  const int tid = threadIdx.x;
  const int wid = tid >> 6, lane = tid & 63;
  const int coH = wid >> 1, ns = wid & 1;
  const int n32 = lane & 31, half = lane >> 5;
  const int owL = n32 & 15, doh = n32 >> 4;
  const int ihBase = 2 * oh0 - 1, iwBase = 2 * ow0 - 1;
  const int wlane = (coH * 128 + n32) * 16 + half * 8;

  fx16 zz;
#pragma unroll
  for (int e = 0; e < 16; e++) zz[e] = 0.f;
  fx16 acc[4][2];
#pragma unroll
  for (int mf = 0; mf < 4; mf++)
#pragma unroll
    for (int nf = 0; nf < 2; nf++) acc[mf][nf] = zz;

  // per-thread staging slots (5 x uint4), precomputed addresses
  uint4 z4 = {0u, 0u, 0u, 0u};
  uint4 rv0, rv1, rv2, rv3, rv4;
  int sAddr[5];      // LDS 16B-unit index
  size_t gOff[5];    // global element offset (w/o cib term)
  bool gOk[5];
#pragma unroll
  for (int t = 0; t < 5; t++) {
    int S = tid + t * 256;
    sAddr[t] = -1;
    gOff[t] = 0;
    gOk[t] = false;
    if (S < 1122) {
      int p = S >> 1, h = S & 1;
      int ihr = p / 33, se = p - ihr * 33;
      int iwr = (se < 17) ? 2 * se : 2 * (se - 17) + 1;
      int ih = ihBase + ihr, iw = iwBase + iwr;
      sAddr[t] = (p * 2 + h) ^ ((se >> 2) & 1);
      if (ih >= 0 && ih < H && iw >= 0 && iw < H) {
        gOk[t] = true;
        gOff[t] = (size_t)(ih * H + iw) * 256 + h * 8;
      }
    }
  }

#define ISSUE(cib)                                                       \
  {                                                                      \
    int ci0 = (cib) * 16;                                                \
    rv0 = gOk[0] ? *(const uint4*)(X + gOff[0] + ci0) : z4;              \
    rv1 = gOk[1] ? *(const uint4*)(X + gOff[1] + ci0) : z4;              \
    rv2 = gOk[2] ? *(const uint4*)(X + gOff[2] + ci0) : z4;              \
    rv3 = gOk[3] ? *(const uint4*)(X + gOff[3] + ci0) : z4;              \
    rv4 = gOk[4] ? *(const uint4*)(X + gOff[4] + ci0) : z4;              \
  }
#define COMMIT(bufi)                                                     \
  {                                                                      \
    if (sAddr[0] >= 0) *(uint4*)&sB[bufi][sAddr[0] * 8] = rv0;           \
    if (sAddr[1] >= 0) *(uint4*)&sB[bufi][sAddr[1] * 8] = rv1;           \
    if (sAddr[2] >= 0) *(uint4*)&sB[bufi][sAddr[2] * 8] = rv2;           \
    if (sAddr[3] >= 0) *(uint4*)&sB[bufi][sAddr[3] * 8] = rv3;           \
    if (sAddr[4] >= 0) *(uint4*)&sB[bufi][sAddr[4] * 8] = rv4;           \
  }

  ISSUE(0);
  COMMIT(0);
  __syncthreads();
  int buf = 0;
  for (int cib = 0; cib < 16; cib++) {
    if (cib < 15) ISSUE(cib + 1);
    __builtin_amdgcn_s_setprio(1);
#pragma unroll
    for (int kh = 0; kh < 3; kh++) {
#pragma unroll
      for (int kw = 0; kw < 3; kw++) {
        const int k = kh * 3 + kw;
        const size_t wo = ((size_t)(k * 16 + cib)) * 4096 + wlane;
        f16x8 ah[4], al[4];
#pragma unroll
        for (int mf = 0; mf < 4; mf++) {
          ah[mf] = *(const f16x8*)(WH + wo + mf * 512);
          al[mf] = *(const f16x8*)(WL + wo + mf * 512);
        }
#pragma unroll
        for (int nf = 0; nf < 2; nf++) {
          int ohL = ns * 4 + nf * 2 + doh;
          int ihr = 2 * ohL + kh;
          int se = (kw == 1) ? 17 + owL : owL + (kw >> 1);
          int p = ihr * 33 + se;
          int a16 = (p * 2 + half) ^ ((se >> 2) & 1);
          f16x8 bf = *(const f16x8*)&sB[buf][a16 * 8];
#pragma unroll
          for (int mf = 0; mf < 4; mf++) {
            acc[mf][nf] = mfma16(ah[mf], bf, acc[mf][nf]);
            acc[mf][nf] = mfma16(al[mf], bf, acc[mf][nf]);
          }
        }
      }
    }
    __builtin_amdgcn_s_setprio(0);
    if (cib < 15) {
      COMMIT(buf ^ 1);
      __syncthreads();
      buf ^= 1;
    }
  }
#undef ISSUE
#undef COMMIT

  const float* cb = a.cb[set];
  const int ow = ow0 + owL;
#pragma unroll
  for (int mf = 0; mf < 4; mf++) {
#pragma unroll
    for (int nf = 0; nf < 2; nf++) {
      int oh = oh0 + ns * 4 + nf * 2 + doh;
      if (oh < OH && ow < OW) {
#pragma unroll
        for (int reg = 0; reg < 16; reg++) {
          int row = (reg & 3) + 8 * (reg >> 2) + 4 * half;
          int co = coH * 128 + mf * 32 + row;
          float v = acc[mf][nf][reg] + cb[co];
          yout[(size_t)co * OHWp + oh * OW + ow] = f2bf(v);
        }
      }
    }
  }
}

// ---------------- BN stats over bf16 y --------------------------------------
struct RedArgs { const ushort* y[16]; float* mv; int ohw[16]; int ohwp[16]; };
__global__ __launch_bounds__(256) void bn_reduce_k(RedArgs a) {
  const int c = blockIdx.x, p = blockIdx.y;
  const int ohwp = a.ohwp[p];
  const int n8 = ohwp >> 3;
  float s = 0.f, s2 = 0.f;
  for (int b = 0; b < 2; b++) {
    const ushort* base = a.y[p] + (size_t)(b * 256 + c) * ohwp;
    for (int i = threadIdx.x; i < n8; i += 256) {
      uint4 v = *(const uint4*)(base + i * 8);
      uint ua[4] = {v.x, v.y, v.z, v.w};
#pragma unroll
      for (int w = 0; w < 4; w++) {
        float f0 = bf2f((ushort)(ua[w] & 0xffffu));
        float f1 = bf2f((ushort)(ua[w] >> 16));
        s += f0 + f1;
        s2 += f0 * f0 + f1 * f1;
      }
    }
  }
  __shared__ float rs[4], rs2[4];
  for (int off = 32; off > 0; off >>= 1) { s += __shfl_down(s, off); s2 += __shfl_down(s2, off); }
  int wid = threadIdx.x >> 6, lanei = threadIdx.x & 63;
  if (lanei == 0) { rs[wid] = s; rs2[wid] = s2; }
  __syncthreads();
  if (threadIdx.x == 0) {
    float S = 0.f, S2 = 0.f;
    for (int w = 0; w < 4; w++) { S += rs[w]; S2 += rs2[w]; }
    float n = (float)(2 * a.ohw[p]);
    float m = S / n;
    a.mv[p * 512 + c] = m;
    a.mv[p * 512 + 256 + c] = S2 / n - m * m;
  }
}

// ---------------- fea[p,b,c] = mean_spatial( leaky(BN(y)) ) ------------------
struct FeaArgs { const ushort* y[16]; const float* g[16]; const float* beta[16];
                 const float* mv; float* fea; int ohw[16]; int ohwp[16]; };
__global__ __launch_bounds__(256) void fea_k(FeaArgs a) {
  const int c = blockIdx.x;
  const int z = blockIdx.y;
  const int p = z >> 1, b = z & 1;
  const int ohw = a.ohw[p], ohwp = a.ohwp[p];
  const int n8 = ohwp >> 3;
  float m = a.mv[p * 512 + c], v = a.mv[p * 512 + 256 + c];
  float rsq = 1.0f / sqrtf(v + 1e-5f);
  float gg = a.g[p][c] * rsq;
  float bb = a.beta[p][c] - m * gg;
  const ushort* base = a.y[p] + (size_t)(b * 256 + c) * ohwp;
  float s = 0.f;
  for (int i = threadIdx.x; i < n8; i += 256) {
    uint4 vv = *(const uint4*)(base + i * 8);
    uint ua[4] = {vv.x, vv.y, vv.z, vv.w};
#pragma unroll
    for (int w = 0; w < 4; w++) {
      int e = i * 8 + w * 2;
      float f0 = bf2f((ushort)(ua[w] & 0xffffu));
      float f1 = bf2f((ushort)(ua[w] >> 16));
      if (e < ohw) s += leaky_f(f0 * gg + bb);
      if (e + 1 < ohw) s += leaky_f(f1 * gg + bb);
    }
  }
  __shared__ float rsm[4];
  for (int off = 32; off > 0; off >>= 1) s += __shfl_down(s, off);
  int wid = threadIdx.x >> 6, lanei = threadIdx.x & 63;
  if (lanei == 0) rsm[wid] = s;
  __syncthreads();
  if (threadIdx.x == 0) {
    float S = rsm[0] + rsm[1] + rsm[2] + rsm[3];
    a.fea[((size_t)p * 2 + b) * 256 + c] = S / (float)ohw;
  }
}

// ---------------- 2-layer MLP per pass ---------------------------------------
struct MlpArgs { const float* fea; const float* w1[16]; const float* b1[16];
                 const float* w2[16]; const float* b2[16]; float* enc; };
__global__ __launch_bounds__(512) void mlp_k(MlpArgs a) {
  const int p = blockIdx.x;
  const int t = threadIdx.x;
  const int b = t >> 8, co = t & 255;
  __shared__ float sfea[2][256];
  __shared__ float sh[2][256];
  sfea[b][co] = a.fea[((size_t)p * 2 + b) * 256 + co];
  __syncthreads();
  {
    const float* w1 = a.w1[p] + (size_t)co * 256;
    float s = a.b1[p][co];
    for (int ci = 0; ci < 256; ci += 4) {
      float4 wv = ld4(&w1[ci]);
      s += wv.x * sfea[b][ci] + wv.y * sfea[b][ci + 1] + wv.z * sfea[b][ci + 2] + wv.w * sfea[b][ci + 3];
    }
    sh[b][co] = leaky_f(s);
  }
  __syncthreads();
  {
    const float* w2 = a.w2[p] + (size_t)co * 256;
    float s = a.b2[p][co];
    for (int ci = 0; ci < 256; ci += 4) {
      float4 wv = ld4(&w2[ci]);
      s += wv.x * sh[b][ci] + wv.y * sh[b][ci + 1] + wv.z * sh[b][ci + 2] + wv.w * sh[b][ci + 3];
    }
    a.enc[((size_t)p * 2 + b) * 256 + co] = s;
  }
}

// ---------------- final loss -------------------------------------------------
__global__ __launch_bounds__(256) void loss_k(const float* __restrict__ enc, float* __restrict__ out) {
  __shared__ float nv[32][256];
  __shared__ float norms[32];
  __shared__ float sE[4][64];
  const int tid = threadIdx.x;
  if (tid < 32) {
    const float* v = enc + (size_t)tid * 256;
    float s = 0.f;
    for (int i = 0; i < 256; i++) s += v[i] * v[i];
    norms[tid] = fmaxf(sqrtf(s), 1e-12f);
  }
  __syncthreads();
  for (int idx = tid; idx < 8192; idx += 256) {
    int vi = idx >> 8, c = idx & 255;
    nv[vi][c] = enc[idx] / norms[vi];
  }
  __syncthreads();
  {
    int m = tid >> 6, e = tid & 63;
    int i = e >> 4, b = (e >> 3) & 1, k = (e >> 1) & 3, l = e & 1;
    int ga = (m < 2) ? 1 : 3;
    int gb = (m == 0) ? 1 : (m == 1) ? 0 : (m == 2) ? 3 : 2;
    const float* va = nv[ga * 8 + i * 2 + b];
    const float* vb = nv[gb * 8 + k * 2 + l];
    float d = 0.f;
    for (int c = 0; c < 256; c++) d += va[c] * vb[c];
    sE[m][e] = expf(d * 2.0f);
  }
  __syncthreads();
  if (tid == 0) {
    float geo = 0.f;
    for (int i = 0; i < 4; i++)
      for (int b = 0; b < 2; b++) {
        float num = sE[1][i * 16 + b * 8 + i * 2 + b];
        float den = num;
        for (int k = 0; k < 4; k++)
          for (int l = 0; l < 2; l++)
            if (k != i && l != b)
              den += sE[0][i * 16 + b * 8 + k * 2 + l] + sE[1][i * 16 + b * 8 + k * 2 + l];
        geo -= logf(num / den);
      }
    out[0] = geo;
    float sem = 0.f;
    for (int i = 0; i < 3; i++)
      for (int b = 0; b < 2; b++) {
        float num = sE[2][i * 16 + b * 8 + (i + 1) * 2 + b];
        float den = num;
        for (int k = 0; k < 4; k++)
          for (int l = 0; l < 2; l++)
            if (l != b)
              den += sE[2][i * 16 + b * 8 + k * 2 + l] + sE[3][i * 16 + b * 8 + k * 2 + l];
        sem -= logf(num / den);
      }
    out[1] = sem;
  }
}

// ---------------- host launcher ---------------------------------------------
extern "C" void kernel_launch(void* const* d_in, const int* in_sizes, int n_in,
                              void* d_out, int out_size, void* d_ws, size_t ws_size,
                              hipStream_t stream) {
  (void)in_sizes; (void)n_in; (void)out_size; (void)ws_size;
  const float* xb[4] = {(const float*)d_in[0], (const float*)d_in[1],
                        (const float*)d_in[2], (const float*)d_in[3]};
  const float* xs[4] = {(const float*)d_in[4], (const float*)d_in[5],
                        (const float*)d_in[6], (const float*)d_in[7]};
  const float* ct_w[4] = {(const float*)d_in[8], (const float*)d_in[10],
                          (const float*)d_in[12], (const float*)d_in[14]};
  const float* ct_b[4] = {(const float*)d_in[9], (const float*)d_in[11],
                          (const float*)d_in[13], (const float*)d_in[15]};
  const float* loc_cw = (const float*)d_in[16];
  const float* loc_cb = (const float*)d_in[17];
  const float* loc_g  = (const float*)d_in[18];
  const float* loc_bt = (const float*)d_in[19];
  const float* loc_w1 = (const float*)d_in[20];
  const float* loc_b1 = (const float*)d_in[21];
  const float* loc_w2 = (const float*)d_in[22];
  const float* loc_b2 = (const float*)d_in[23];
  const float* sem_cw = (const float*)d_in[24];
  const float* sem_cb = (const float*)d_in[25];
  const float* sem_g  = (const float*)d_in[26];
  const float* sem_bt = (const float*)d_in[27];
  const float* sem_w1 = (const float*)d_in[28];
  const float* sem_b1 = (const float*)d_in[29];
  const float* sem_w2 = (const float*)d_in[30];
  const float* sem_b2 = (const float*)d_in[31];

  static const int Hs[4]   = {200, 100, 50, 25};
  static const int OHs[4]  = {100, 50, 25, 13};
  static const int OHWp[4] = {10000, 2504, 632, 176};
  static const int CIN[4]  = {256, 512, 1024, 2048};
  static const int nOwT[4] = {7, 4, 2, 1};
  static const int nOhT[4] = {13, 7, 4, 2};
  static const size_t preHW[4] = {0, 40000, 50000, 52500};

  char* base = (char*)d_ws;
  size_t off = 0;
  auto alloc = [&](size_t bytes) -> char* {
    char* p = base + off;
    off = (off + bytes + 255) & ~(size_t)255;
    return p;
  };

  _Float16* W1H = (_Float16*)alloc((size_t)983040 * 2);   // sum(Cin)*256
  _Float16* W1L = (_Float16*)alloc((size_t)983040 * 2);
  _Float16* W3H = (_Float16*)alloc((size_t)2 * 589824 * 2);
  _Float16* W3L = (_Float16*)alloc((size_t)2 * 589824 * 2);
  _Float16* xbT = (_Float16*)alloc((size_t)38400000 * 2);  // 2*sum(HW*Cin)
  _Float16* xsT = (_Float16*)alloc((size_t)2 * 53125 * 256 * 2);
  _Float16* tbT = (_Float16*)alloc((size_t)2 * 53125 * 256 * 2);
  size_t ytot = 0;
  for (int p = 0; p < 16; p++) ytot += (size_t)2 * 256 * OHWp[p & 3] * 2;
  char* yAll = alloc(ytot);
  ushort* y[16];
  {
    size_t c = 0;
    for (int p = 0; p < 16; p++) {
      y[p] = (ushort*)(yAll + c);
      c += (size_t)2 * 256 * OHWp[p & 3] * 2;
    }
  }
  float* mv  = (float*)alloc(16 * 512 * 4);
  float* fea = (float*)alloc(16 * 512 * 4);
  float* enc = (float*)alloc(16 * 512 * 4);

  // per-scale offsets
  size_t w1Off[4], xbOff[4];
  {
    size_t cw = 0, cx = 0;
    for (int s = 0; s < 4; s++) {
      w1Off[s] = cw; cw += (size_t)CIN[s] * 256;
      xbOff[s] = cx; cx += (size_t)2 * Hs[s] * Hs[s] * CIN[s];
    }
  }

  // 1. weight preps
  {
    W1PArgs wp;
    for (int s = 0; s < 4; s++) {
      wp.w[s] = ct_w[s]; wp.oH[s] = W1H + w1Off[s]; wp.oL[s] = W1L + w1Off[s];
      wp.Cin[s] = CIN[s];
    }
    w1prep_k<<<dim3(128, 4), dim3(256), 0, stream>>>(wp);
  }
  w3prep_k<<<dim3(2048), dim3(256), 0, stream>>>(loc_cw, sem_cw, W3H, W3L);

  // 2. transposes: xb -> xbT (var Cin), xs -> xsT (Cin=256)
  for (int s = 0; s < 4; s++) {
    int HW = Hs[s] * Hs[s];
    xT_k<<<dim3((HW + 63) / 64, CIN[s] / 32, 2), dim3(256), 0, stream>>>(
        xb[s], xbT + xbOff[s], HW, CIN[s]);
  }
  for (int s = 0; s < 4; s++) {
    int HW = Hs[s] * Hs[s];
    xT_k<<<dim3((HW + 63) / 64, 8, 2), dim3(256), 0, stream>>>(
        xs[s], xsT + preHW[s] * 512, HW, 256);
  }

  // 3. conv1x1 MFMA -> tbT
  {
    G1Args g;
    static const int nT[4] = {313, 79, 20, 5};
    g.cumT[0] = 0;
    for (int s = 0; s < 4; s++) {
      g.x[s] = xbT + xbOff[s];
      g.wH[s] = W1H + w1Off[s];
      g.wL[s] = W1L + w1Off[s];
      g.bias[s] = ct_b[s];
      g.out[s] = tbT + preHW[s] * 512;
      g.HW[s] = Hs[s] * Hs[s];
      g.Cin[s] = CIN[s];
      g.cumT[s + 1] = g.cumT[s] + nT[s];
    }
    g1x1_k<<<dim3(g.cumT[4], 1, 2), dim3(256), 0, stream>>>(g);
  }

  // 4. zero y (pads must be zero for BN sums)
  hipMemsetAsync(yAll, 0, ytot, stream);

  // 5. conv3x3 encoders
  {
    C3Args a;
    for (int s = 0; s < 4; s++) {
      a.in[0][s] = tbT + preHW[s] * 512;
      a.in[1][s] = xsT + preHW[s] * 512;
      a.H[s] = Hs[s]; a.OH[s] = OHs[s]; a.OW[s] = OHs[s];
      a.OHWp[s] = OHWp[s]; a.nOwT[s] = nOwT[s];
    }
    a.w3H = W3H; a.w3L = W3L;
    a.cb[0] = loc_cb; a.cb[1] = sem_cb;
    for (int p = 0; p < 16; p++) a.y[p] = y[p];
    a.cumTiles[0] = 0;
    for (int s = 0; s < 4; s++) a.cumTiles[s + 1] = a.cumTiles[s] + nOwT[s] * nOhT[s];
    conv3_k<<<dim3(a.cumTiles[4], 4, 2), dim3(256), 0, stream>>>(a);
  }

  // 6. BN stats
  {
    RedArgs r;
    for (int p = 0; p < 16; p++) {
      r.y[p] = y[p];
      r.ohw[p] = OHs[p & 3] * OHs[p & 3];
      r.ohwp[p] = OHWp[p & 3];
    }
    r.mv = mv;
    bn_reduce_k<<<dim3(256, 16), dim3(256), 0, stream>>>(r);
  }

  // 7. fea
  {
    FeaArgs f;
    for (int p = 0; p < 16; p++) {
      f.y[p] = y[p];
      f.ohw[p] = OHs[p & 3] * OHs[p & 3];
      f.ohwp[p] = OHWp[p & 3];
      f.g[p]    = (p < 8) ? loc_g  : sem_g;
      f.beta[p] = (p < 8) ? loc_bt : sem_bt;
    }
    f.mv = mv; f.fea = fea;
    fea_k<<<dim3(256, 32), dim3(256), 0, stream>>>(f);
  }

  // 8. MLPs
  {
    MlpArgs m;
    for (int p = 0; p < 16; p++) {
      m.w1[p] = (p < 8) ? loc_w1 : sem_w1;
      m.b1[p] = (p < 8) ? loc_b1 : sem_b1;
      m.w2[p] = (p < 8) ? loc_w2 : sem_w2;
      m.b2[p] = (p < 8) ? loc_b2 : sem_b2;
    }
    m.fea = fea; m.enc = enc;
    mlp_k<<<dim3(16), dim3(512), 0, stream>>>(m);
  }

  // 9. loss
  loss_k<<<dim3(1), dim3(256), 0, stream>>>(enc, (float*)d_out);
}